// Round 2
// baseline (1050.590 us; speedup 1.0000x reference)
//
#include <hip/hip_runtime.h>

// ---------------------------------------------------------------- constants
#define H_   32
#define D_   128
#define HID_ 4096
#define B_   4
#define S_   1024
#define T_   4096
#define NSLOTS_ 16384
#define NQKV_ 4352   // HID + 2*D

typedef __attribute__((ext_vector_type(8))) __bf16 bf16x8;
typedef __attribute__((ext_vector_type(4))) __bf16 bf16x4;
typedef __attribute__((ext_vector_type(4))) float  f32x4;

// ---------------------------------------------------------------- cast fp32 -> bf16 (vectorized)
__global__ __launch_bounds__(256) void cast_bf16_kernel(
    const float* __restrict__ in, __bf16* __restrict__ out, int n4)
{
    int i = blockIdx.x * 256 + threadIdx.x;
    if (i < n4) {
        f32x4 v = ((const f32x4*)in)[i];
        bf16x4 o;
        o[0] = (__bf16)v[0]; o[1] = (__bf16)v[1];
        o[2] = (__bf16)v[2]; o[3] = (__bf16)v[3];
        ((bf16x4*)out)[i] = o;
    }
}

// ---------------------------------------------------------------- transpose + cast: in (R x C) f32 -> out (C x R) bf16
__global__ __launch_bounds__(256) void transpose_cast_kernel(
    const float* __restrict__ in, __bf16* __restrict__ out, int R, int C)
{
    __shared__ float tile[32][33];
    int c0 = blockIdx.x * 32, r0 = blockIdx.y * 32;
    int tx = threadIdx.x;   // 0..31
    int ty = threadIdx.y;   // 0..7
#pragma unroll
    for (int j = 0; j < 32; j += 8)
        tile[ty + j][tx] = in[(size_t)(r0 + ty + j) * C + c0 + tx];
    __syncthreads();
#pragma unroll
    for (int j = 0; j < 32; j += 8)
        out[(size_t)(c0 + ty + j) * R + r0 + tx] = (__bf16)tile[tx][ty + j];
}

// ---------------------------------------------------------------- bf16 MFMA GEMM
// C(MxN, f32) = A(MxK, bf16 row-major) * Bt(NxK, bf16 row-major)^T + bias(N)
// 128x128 block tile, BK=32, 4 waves each 64x64 (4x4 MFMA tiles of 16x16x32)
#define GBK 32
#define GLDA 40   // padded row stride (elements); 80B, 16B-aligned, 2-way bank alias only
__global__ __launch_bounds__(256) void gemm_bf16_kernel(
    const __bf16* __restrict__ A, const __bf16* __restrict__ Bt,
    const float* __restrict__ bias, float* __restrict__ C,
    int M, int N, int K)
{
    __shared__ __bf16 sA[128][GLDA];
    __shared__ __bf16 sB[128][GLDA];

    const int tid  = threadIdx.x;
    const int lane = tid & 63;
    const int wave = tid >> 6;
    const int wm   = wave >> 1;   // 0..1
    const int wn   = wave & 1;    // 0..1
    const int col  = lane & 15;
    const int quad = lane >> 4;
    const int bm = blockIdx.y * 128;
    const int bn = blockIdx.x * 128;

    f32x4 acc[4][4];
#pragma unroll
    for (int mt = 0; mt < 4; ++mt)
#pragma unroll
        for (int nt = 0; nt < 4; ++nt)
#pragma unroll
            for (int r = 0; r < 4; ++r) acc[mt][nt][r] = 0.f;

    const int srow = tid >> 2;          // 0..63  (staging row block of 64 per iter)
    const int sc8  = (tid & 3) * 8;     // 0,8,16,24

    for (int k0 = 0; k0 < K; k0 += GBK) {
        __syncthreads();
        // stage A & B tiles: 128 rows x 32 cols each; thread does 2 chunks per array
#pragma unroll
        for (int i = 0; i < 2; ++i) {
            int row = srow + i * 64;
            *(uint4*)&sA[row][sc8] = *(const uint4*)&A[(size_t)(bm + row) * K + k0 + sc8];
            *(uint4*)&sB[row][sc8] = *(const uint4*)&Bt[(size_t)(bn + row) * K + k0 + sc8];
        }
        __syncthreads();

        bf16x8 af[4], bf[4];
#pragma unroll
        for (int mt = 0; mt < 4; ++mt)
            af[mt] = *(const bf16x8*)&sA[wm * 64 + mt * 16 + col][quad * 8];
#pragma unroll
        for (int nt = 0; nt < 4; ++nt)
            bf[nt] = *(const bf16x8*)&sB[wn * 64 + nt * 16 + col][quad * 8];
#pragma unroll
        for (int mt = 0; mt < 4; ++mt)
#pragma unroll
            for (int nt = 0; nt < 4; ++nt)
                acc[mt][nt] = __builtin_amdgcn_mfma_f32_16x16x32_bf16(
                    af[mt], bf[nt], acc[mt][nt], 0, 0, 0);
    }

    // epilogue: D[row][col]: row = quad*4 + r, col = lane&15  (within 16x16 tile)
#pragma unroll
    for (int mt = 0; mt < 4; ++mt) {
#pragma unroll
        for (int nt = 0; nt < 4; ++nt) {
            int r0 = bm + wm * 64 + mt * 16 + quad * 4;
            int c0 = bn + wn * 64 + nt * 16 + col;
            float bv = bias[c0];
#pragma unroll
            for (int r = 0; r < 4; ++r)
                C[(size_t)(r0 + r) * N + c0] = acc[mt][nt][r] + bv;
        }
    }
}

// ---------------------------------------------------------------- RoPE + cache scatter + bf16 q/k/v
// qkv: (T, 4352) f32.  cos/sin: (T, 64) f32.
__global__ __launch_bounds__(256) void rope_scatter_kernel(
    const float* __restrict__ qkv, const float* __restrict__ cosb,
    const float* __restrict__ sinb, const int* __restrict__ slots,
    __bf16* __restrict__ q16, __bf16* __restrict__ k16, __bf16* __restrict__ v16,
    float* __restrict__ kcache, float* __restrict__ vcache)
{
    const int t = blockIdx.x;
    const int tid = threadIdx.x;
    const float* row = qkv + (size_t)t * NQKV_;
    const float* cr = cosb + (size_t)t * 64;
    const float* sr = sinb + (size_t)t * 64;
    const int slot = slots[t];

    // q: 32 heads x 64 rotation pairs = 2048 pairs
#pragma unroll
    for (int i = 0; i < 8; ++i) {
        int p = tid + 256 * i;       // 0..2047
        int h = p >> 6;
        int d = p & 63;
        float x1 = row[h * 128 + d];
        float x2 = row[h * 128 + 64 + d];
        float c = cr[d], s = sr[d];
        q16[(size_t)t * HID_ + h * 128 + d]      = (__bf16)(x1 * c - x2 * s);
        q16[(size_t)t * HID_ + h * 128 + 64 + d] = (__bf16)(x2 * c + x1 * s);
    }
    // k: 64 pairs  (k = qkv[:, HID : HID+128])
    if (tid < 64) {
        int d = tid;
        float x1 = row[HID_ + d];
        float x2 = row[HID_ + 64 + d];
        float c = cr[d], s = sr[d];
        float o1 = x1 * c - x2 * s;
        float o2 = x2 * c + x1 * s;
        kcache[(size_t)slot * D_ + d]      = o1;
        kcache[(size_t)slot * D_ + 64 + d] = o2;
        k16[(size_t)t * D_ + d]      = (__bf16)o1;
        k16[(size_t)t * D_ + 64 + d] = (__bf16)o2;
    }
    // v: 128 elems  (v = qkv[:, HID+128 : HID+256])
    if (tid < 128) {
        float v = row[HID_ + 128 + tid];
        vcache[(size_t)slot * D_ + tid] = v;
        v16[(size_t)t * D_ + tid] = (__bf16)v;
    }
}

// ---------------------------------------------------------------- flash MQA attention (bf16 MFMA)
// Q: (T, HID) bf16 rope'd.  K,V: (T, D) bf16.  O: (T, HID) bf16.
// block = (q-tile 128, head, batch); 4 waves, wave w owns 32 q-rows.
__global__ __launch_bounds__(256) void attn_kernel(
    const __bf16* __restrict__ Q, const __bf16* __restrict__ Kc,
    const __bf16* __restrict__ Vc, __bf16* __restrict__ O)
{
    __shared__ __bf16 sK[64][136];      // k-tile (s x d), row-major: B^T layout for QK^T
    __shared__ __bf16 sVt[128][72];     // V transposed (d x s): B^T layout for PV
    __shared__ __bf16 sP[4][32][72];    // per-wave P round-trip (C-layout -> A-layout)

    const int qt = blockIdx.x;   // 0..7
    const int h  = blockIdx.y;   // 0..31
    const int b  = blockIdx.z;   // 0..3
    const int tid = threadIdx.x, lane = tid & 63, wave = tid >> 6;
    const int col = lane & 15, quad = lane >> 4;
    const int qb = qt * 128;
    const int tbase = b * S_;
    const float scale = 0.08838834764831845f; // 1/sqrt(128)

    // Q fragments: 2 m-tiles x 4 k-steps, held in registers for the whole loop
    bf16x8 aq[2][4];
#pragma unroll
    for (int mt = 0; mt < 2; ++mt)
#pragma unroll
        for (int ks = 0; ks < 4; ++ks)
            aq[mt][ks] = *(const bf16x8*)&Q[(size_t)(tbase + qb + wave * 32 + mt * 16 + col) * HID_
                                            + h * 128 + ks * 32 + quad * 8];

    f32x4 o[2][8];
#pragma unroll
    for (int mt = 0; mt < 2; ++mt)
#pragma unroll
        for (int nd = 0; nd < 8; ++nd)
#pragma unroll
            for (int r = 0; r < 4; ++r) o[mt][nd][r] = 0.f;
    float m_i[2][4], l_i[2][4];
#pragma unroll
    for (int mt = 0; mt < 2; ++mt)
#pragma unroll
        for (int r = 0; r < 4; ++r) { m_i[mt][r] = -3.0e38f; l_i[mt][r] = 0.f; }

    const int ntiles = qt * 2 + 2;   // causal: k-tiles of 64 up to qb+128
    for (int kt = 0; kt < ntiles; ++kt) {
        const int kb = kt * 64;
        __syncthreads();
        // stage K (64 x 128) row-major
#pragma unroll
        for (int i = 0; i < 4; ++i) {
            int c = tid + i * 256;           // 0..1023
            int srow = c >> 4;               // 0..63
            int d0 = (c & 15) * 8;
            *(uint4*)&sK[srow][d0] = *(const uint4*)&Kc[(size_t)(tbase + kb + srow) * D_ + d0];
        }
        // stage V transposed (d x s)
#pragma unroll
        for (int i = 0; i < 4; ++i) {
            int c = tid + i * 256;
            int srow = c >> 4;
            int d0 = (c & 15) * 8;
            bf16x8 v = *(const bf16x8*)&Vc[(size_t)(tbase + kb + srow) * D_ + d0];
#pragma unroll
            for (int j = 0; j < 8; ++j) sVt[d0 + j][srow] = v[j];
        }
        __syncthreads();

        // QK^T: per wave 32x64 scores
        f32x4 sc[2][4];
#pragma unroll
        for (int mt = 0; mt < 2; ++mt)
#pragma unroll
            for (int nt = 0; nt < 4; ++nt)
#pragma unroll
                for (int r = 0; r < 4; ++r) sc[mt][nt][r] = 0.f;
#pragma unroll
        for (int ks = 0; ks < 4; ++ks) {
            bf16x8 bk[4];
#pragma unroll
            for (int nt = 0; nt < 4; ++nt)
                bk[nt] = *(const bf16x8*)&sK[nt * 16 + col][ks * 32 + quad * 8];
#pragma unroll
            for (int mt = 0; mt < 2; ++mt)
#pragma unroll
                for (int nt = 0; nt < 4; ++nt)
                    sc[mt][nt] = __builtin_amdgcn_mfma_f32_16x16x32_bf16(
                        aq[mt][ks], bk[nt], sc[mt][nt], 0, 0, 0);
        }

        // scale + causal mask + online softmax
#pragma unroll
        for (int mt = 0; mt < 2; ++mt) {
#pragma unroll
            for (int r = 0; r < 4; ++r) {
                int qrow = qb + wave * 32 + mt * 16 + quad * 4 + r;
#pragma unroll
                for (int nt = 0; nt < 4; ++nt) {
                    float v = sc[mt][nt][r] * scale;
                    int kcol = kb + nt * 16 + col;
                    sc[mt][nt][r] = (kcol > qrow) ? -3.0e38f : v;
                }
                float mx = sc[mt][0][r];
#pragma unroll
                for (int nt = 1; nt < 4; ++nt) mx = fmaxf(mx, sc[mt][nt][r]);
#pragma unroll
                for (int x = 1; x < 16; x <<= 1) mx = fmaxf(mx, __shfl_xor(mx, x, 64));
                float mnew = fmaxf(m_i[mt][r], mx);
                float alpha = __expf(m_i[mt][r] - mnew);
                m_i[mt][r] = mnew;
                float rs = 0.f;
#pragma unroll
                for (int nt = 0; nt < 4; ++nt) {
                    float p = __expf(sc[mt][nt][r] - mnew);
                    sc[mt][nt][r] = p;
                    rs += p;
                }
#pragma unroll
                for (int x = 1; x < 16; x <<= 1) rs += __shfl_xor(rs, x, 64);
                l_i[mt][r] = l_i[mt][r] * alpha + rs;
#pragma unroll
                for (int nd = 0; nd < 8; ++nd) o[mt][nd][r] *= alpha;
            }
        }

        // P: C-layout regs -> per-wave LDS (bf16)
#pragma unroll
        for (int mt = 0; mt < 2; ++mt)
#pragma unroll
            for (int nt = 0; nt < 4; ++nt)
#pragma unroll
                for (int r = 0; r < 4; ++r)
                    sP[wave][mt * 16 + quad * 4 + r][nt * 16 + col] = (__bf16)sc[mt][nt][r];
        __syncthreads();

        // PV: O(32 x 128) += P(32 x 64) * V(64 x 128)
#pragma unroll
        for (int ks2 = 0; ks2 < 2; ++ks2) {
            bf16x8 ap[2];
#pragma unroll
            for (int mt = 0; mt < 2; ++mt)
                ap[mt] = *(const bf16x8*)&sP[wave][mt * 16 + col][ks2 * 32 + quad * 8];
#pragma unroll
            for (int nd = 0; nd < 8; ++nd) {
                bf16x8 bv = *(const bf16x8*)&sVt[nd * 16 + col][ks2 * 32 + quad * 8];
#pragma unroll
                for (int mt = 0; mt < 2; ++mt)
                    o[mt][nd] = __builtin_amdgcn_mfma_f32_16x16x32_bf16(
                        ap[mt], bv, o[mt][nd], 0, 0, 0);
            }
        }
    }

    // epilogue: O /= l, write bf16 (T, HID)
#pragma unroll
    for (int mt = 0; mt < 2; ++mt) {
#pragma unroll
        for (int r = 0; r < 4; ++r) {
            int t = tbase + qb + wave * 32 + mt * 16 + quad * 4 + r;
            float inv_l = 1.f / l_i[mt][r];
#pragma unroll
            for (int nd = 0; nd < 8; ++nd)
                O[(size_t)t * HID_ + h * 128 + nd * 16 + col] = (__bf16)(o[mt][nd][r] * inv_l);
        }
    }
}

// ---------------------------------------------------------------- launch
extern "C" void kernel_launch(void* const* d_in, const int* in_sizes, int n_in,
                              void* d_out, int out_size, void* d_ws, size_t ws_size,
                              hipStream_t stream)
{
    const float* hidden  = (const float*)d_in[0];
    const float* cosb    = (const float*)d_in[1];
    const float* sinb    = (const float*)d_in[2];
    const float* kc_in   = (const float*)d_in[3];
    const float* vc_in   = (const float*)d_in[4];
    const float* qkv_w   = (const float*)d_in[5];
    const float* qkv_b   = (const float*)d_in[6];
    const float* dense_w = (const float*)d_in[7];
    const float* dense_b = (const float*)d_in[8];
    const int*   slots   = (const int*)d_in[9];

    float* out    = (float*)d_out;
    float* kc_out = out + (size_t)T_ * HID_;
    float* vc_out = kc_out + (size_t)NSLOTS_ * D_;

    // workspace layout (peak ~140.5 MB):
    //   [0, 33.5MB)        hidden bf16   -> later reused as attn bf16
    //   [33.5MB, 69.2MB)   W1^T bf16 (4352 x 4096)
    //   [69.2MB, 140.5MB)  qkv f32 (4096 x 4352) -> later reused as W2^T bf16
    char* ws = (char*)d_ws;
    __bf16* A16 = (__bf16*)(ws);
    __bf16* W1T = (__bf16*)(ws + 33554432);
    float*  QKV = (float*)(ws + 69206016);
    __bf16* W2T = (__bf16*)(ws + 69206016);   // alias: qkv f32 dead after rope
    // q/k/v bf16 staged inside d_out's `out` region (dead before GEMM2 writes it)
    __bf16* Q16 = (__bf16*)d_out;
    __bf16* K16 = (__bf16*)((char*)d_out + 33554432);
    __bf16* V16 = (__bf16*)((char*)d_out + 34603008);

    // 1. cast hidden -> bf16
    cast_bf16_kernel<<<(T_ * HID_ / 4 + 255) / 256, 256, 0, stream>>>(hidden, A16, T_ * HID_ / 4);
    // 2. transpose-cast qkv_w (HID x NQKV) -> W1T (NQKV x HID)
    transpose_cast_kernel<<<dim3(NQKV_ / 32, HID_ / 32), dim3(32, 8), 0, stream>>>(qkv_w, W1T, HID_, NQKV_);
    // 3. QKV GEMM
    gemm_bf16_kernel<<<dim3(NQKV_ / 128, T_ / 128), 256, 0, stream>>>(A16, W1T, qkv_b, QKV, T_, NQKV_, HID_);
    // 4. cache pass-through (unwritten slots must equal input caches)
    hipMemcpyAsync(kc_out, kc_in, (size_t)NSLOTS_ * D_ * 4, hipMemcpyDeviceToDevice, stream);
    hipMemcpyAsync(vc_out, vc_in, (size_t)NSLOTS_ * D_ * 4, hipMemcpyDeviceToDevice, stream);
    // 5. RoPE + scatter + bf16 q/k/v
    rope_scatter_kernel<<<T_, 256, 0, stream>>>(QKV, cosb, sinb, slots, Q16, K16, V16, kc_out, vc_out);
    // 6. transpose-cast dense_w (HID x HID) -> W2T (aliases QKV region; runs after rope consumed QKV)
    transpose_cast_kernel<<<dim3(HID_ / 32, HID_ / 32), dim3(32, 8), 0, stream>>>(dense_w, W2T, HID_, HID_);
    // 7. flash MQA attention -> attn bf16 (reuses A16)
    attn_kernel<<<dim3(8, H_, B_), 256, 0, stream>>>(Q16, K16, V16, A16);
    // 8. dense GEMM -> out (f32, overwrites Q16/K16/V16 staging, which is dead)
    gemm_bf16_kernel<<<dim3(HID_ / 128, T_ / 128), 256, 0, stream>>>(A16, W2T, dense_b, out, T_, HID_, HID_);
}

// Round 3
// 820.696 us; speedup vs baseline: 1.2801x; 1.2801x over previous
//
#include <hip/hip_runtime.h>

// ---------------------------------------------------------------- constants
#define H_   32
#define D_   128
#define HID_ 4096
#define B_   4
#define S_   1024
#define T_   4096
#define NSLOTS_ 16384
#define NQKV_ 4352   // HID + 2*D

typedef __attribute__((ext_vector_type(8))) __bf16 bf16x8;
typedef __attribute__((ext_vector_type(4))) __bf16 bf16x4;
typedef __attribute__((ext_vector_type(4))) float  f32x4;

// async global->LDS, 16B per lane; lds dest = wave-uniform base + lane*16
__device__ __forceinline__ void gld_lds16(const __bf16* g, __bf16* l)
{
    __builtin_amdgcn_global_load_lds(
        (const __attribute__((address_space(1))) void*)g,
        (__attribute__((address_space(3))) void*)l, 16, 0, 0);
}

// ---------------------------------------------------------------- cast fp32 -> bf16 (vectorized)
__global__ __launch_bounds__(256) void cast_bf16_kernel(
    const float* __restrict__ in, __bf16* __restrict__ out, int n4)
{
    int i = blockIdx.x * 256 + threadIdx.x;
    if (i < n4) {
        f32x4 v = ((const f32x4*)in)[i];
        bf16x4 o;
        o[0] = (__bf16)v[0]; o[1] = (__bf16)v[1];
        o[2] = (__bf16)v[2]; o[3] = (__bf16)v[3];
        ((bf16x4*)out)[i] = o;
    }
}

// ---------------------------------------------------------------- transpose + cast: in (R x C) f32 -> out (C x R) bf16
__global__ __launch_bounds__(256) void transpose_cast_kernel(
    const float* __restrict__ in, __bf16* __restrict__ out, int R, int C)
{
    __shared__ float tile[32][33];
    int c0 = blockIdx.x * 32, r0 = blockIdx.y * 32;
    int tx = threadIdx.x;   // 0..31
    int ty = threadIdx.y;   // 0..7
#pragma unroll
    for (int j = 0; j < 32; j += 8)
        tile[ty + j][tx] = in[(size_t)(r0 + ty + j) * C + c0 + tx];
    __syncthreads();
#pragma unroll
    for (int j = 0; j < 32; j += 8)
        out[(size_t)(c0 + ty + j) * R + r0 + tx] = (__bf16)tile[tx][ty + j];
}

// ---------------------------------------------------------------- bf16 MFMA GEMM (m97 structure)
// C(MxN, f32) = A(MxK) * Bt(NxK)^T + bias(N); 128x128 tile, BK=32,
// global_load_lds width=16 staging into UNPADDED [128][32] LDS tiles.
#define GBK 32
__global__ __launch_bounds__(256) void gemm_bf16_kernel(
    const __bf16* __restrict__ A, const __bf16* __restrict__ Bt,
    const float* __restrict__ bias, float* __restrict__ C,
    int M, int N, int K)
{
    __shared__ __bf16 sA[128][GBK];   // 8 KB, unpadded (global_load_lds lane order)
    __shared__ __bf16 sB[128][GBK];

    const int tid  = threadIdx.x;
    const int lane = tid & 63;
    const int wave = tid >> 6;
    const int wm   = wave >> 1;   // 0..1
    const int wn   = wave & 1;    // 0..1
    const int col  = lane & 15;
    const int quad = lane >> 4;
    const int bm = blockIdx.y * 128;
    const int bn = blockIdx.x * 128;

    f32x4 acc[4][4];
#pragma unroll
    for (int mt = 0; mt < 4; ++mt)
#pragma unroll
        for (int nt = 0; nt < 4; ++nt)
#pragma unroll
            for (int r = 0; r < 4; ++r) acc[mt][nt][r] = 0.f;

    // staging: wave w covers rows [w*32, w*32+32), two 1KB chunks of 16 rows.
    // lane l: row = l>>2 within chunk, 16B piece (l&3) of the 64B row.
    const int srow = wave * 32 + (lane >> 2);
    const int scol = (lane & 3) * 8;
    const __bf16* gA0 = A  + (size_t)(bm + srow) * K + scol;
    const __bf16* gA1 = A  + (size_t)(bm + srow + 16) * K + scol;
    const __bf16* gB0 = Bt + (size_t)(bn + srow) * K + scol;
    const __bf16* gB1 = Bt + (size_t)(bn + srow + 16) * K + scol;
    __bf16* lA0 = &sA[wave * 32][0];
    __bf16* lA1 = &sA[wave * 32 + 16][0];
    __bf16* lB0 = &sB[wave * 32][0];
    __bf16* lB1 = &sB[wave * 32 + 16][0];

    for (int k0 = 0; k0 < K; k0 += GBK) {
        __syncthreads();
        gld_lds16(gA0 + k0, lA0);
        gld_lds16(gA1 + k0, lA1);
        gld_lds16(gB0 + k0, lB0);
        gld_lds16(gB1 + k0, lB1);
        __syncthreads();

        bf16x8 af[4], bf[4];
#pragma unroll
        for (int mt = 0; mt < 4; ++mt)
            af[mt] = *(const bf16x8*)&sA[wm * 64 + mt * 16 + col][quad * 8];
#pragma unroll
        for (int nt = 0; nt < 4; ++nt)
            bf[nt] = *(const bf16x8*)&sB[wn * 64 + nt * 16 + col][quad * 8];
#pragma unroll
        for (int mt = 0; mt < 4; ++mt)
#pragma unroll
            for (int nt = 0; nt < 4; ++nt)
                acc[mt][nt] = __builtin_amdgcn_mfma_f32_16x16x32_bf16(
                    af[mt], bf[nt], acc[mt][nt], 0, 0, 0);
    }

    // epilogue: D[row][col]: row = quad*4 + r, col = lane&15 (within 16x16 tile)
#pragma unroll
    for (int mt = 0; mt < 4; ++mt) {
#pragma unroll
        for (int nt = 0; nt < 4; ++nt) {
            int r0 = bm + wm * 64 + mt * 16 + quad * 4;
            int c0 = bn + wn * 64 + nt * 16 + col;
            float bv = bias[c0];
#pragma unroll
            for (int r = 0; r < 4; ++r)
                C[(size_t)(r0 + r) * N + c0] = acc[mt][nt][r] + bv;
        }
    }
}

// ---------------------------------------------------------------- RoPE + cache scatter + bf16 q/k/v
__global__ __launch_bounds__(256) void rope_scatter_kernel(
    const float* __restrict__ qkv, const float* __restrict__ cosb,
    const float* __restrict__ sinb, const int* __restrict__ slots,
    __bf16* __restrict__ q16, __bf16* __restrict__ k16, __bf16* __restrict__ v16,
    float* __restrict__ kcache, float* __restrict__ vcache)
{
    const int t = blockIdx.x;
    const int tid = threadIdx.x;
    const float* row = qkv + (size_t)t * NQKV_;
    const float* cr = cosb + (size_t)t * 64;
    const float* sr = sinb + (size_t)t * 64;
    const int slot = slots[t];

#pragma unroll
    for (int i = 0; i < 8; ++i) {
        int p = tid + 256 * i;       // 0..2047
        int h = p >> 6;
        int d = p & 63;
        float x1 = row[h * 128 + d];
        float x2 = row[h * 128 + 64 + d];
        float c = cr[d], s = sr[d];
        q16[(size_t)t * HID_ + h * 128 + d]      = (__bf16)(x1 * c - x2 * s);
        q16[(size_t)t * HID_ + h * 128 + 64 + d] = (__bf16)(x2 * c + x1 * s);
    }
    if (tid < 64) {
        int d = tid;
        float x1 = row[HID_ + d];
        float x2 = row[HID_ + 64 + d];
        float c = cr[d], s = sr[d];
        float o1 = x1 * c - x2 * s;
        float o2 = x2 * c + x1 * s;
        kcache[(size_t)slot * D_ + d]      = o1;
        kcache[(size_t)slot * D_ + 64 + d] = o2;
        k16[(size_t)t * D_ + d]      = (__bf16)o1;
        k16[(size_t)t * D_ + 64 + d] = (__bf16)o2;
    }
    if (tid < 128) {
        float v = row[HID_ + 128 + tid];
        vcache[(size_t)slot * D_ + tid] = v;
        v16[(size_t)t * D_ + tid] = (__bf16)v;
    }
}

// ---------------------------------------------------------------- flash MQA attention (bf16 MFMA)
// grid (4, H, B): block processes q-tiles qt=blockIdx.x AND 7-blockIdx.x
// (uniform 18 k-steps/block -> no causal tail imbalance).
__global__ __launch_bounds__(256) void attn_kernel(
    const __bf16* __restrict__ Q, const __bf16* __restrict__ Kc,
    const __bf16* __restrict__ Vc, __bf16* __restrict__ O)
{
    __shared__ __bf16 sK[64][136];      // k-tile (s x d) row-major
    __shared__ __bf16 sVt[128][72];     // V transposed (d x s)
    __shared__ __bf16 sP[4][32][72];    // per-wave P round-trip (C-layout -> A-layout)

    const int h  = blockIdx.y;
    const int b  = blockIdx.z;
    const int tid = threadIdx.x, lane = tid & 63, wave = tid >> 6;
    const int col = lane & 15, quad = lane >> 4;
    const int tbase = b * S_;
    const float scale = 0.08838834764831845f; // 1/sqrt(128)

    for (int half = 0; half < 2; ++half) {
        const int qt = half ? (7 - blockIdx.x) : blockIdx.x;
        const int qb = qt * 128;

        bf16x8 aq[2][4];
#pragma unroll
        for (int mt = 0; mt < 2; ++mt)
#pragma unroll
            for (int ks = 0; ks < 4; ++ks)
                aq[mt][ks] = *(const bf16x8*)&Q[(size_t)(tbase + qb + wave * 32 + mt * 16 + col) * HID_
                                                + h * 128 + ks * 32 + quad * 8];

        f32x4 o[2][8];
#pragma unroll
        for (int mt = 0; mt < 2; ++mt)
#pragma unroll
            for (int nd = 0; nd < 8; ++nd)
#pragma unroll
                for (int r = 0; r < 4; ++r) o[mt][nd][r] = 0.f;
        float m_i[2][4], l_i[2][4];
#pragma unroll
        for (int mt = 0; mt < 2; ++mt)
#pragma unroll
            for (int r = 0; r < 4; ++r) { m_i[mt][r] = -3.0e38f; l_i[mt][r] = 0.f; }

        const int ntiles = qt * 2 + 2;
        for (int kt = 0; kt < ntiles; ++kt) {
            const int kb = kt * 64;
            __syncthreads();
            // stage K (64 x 128) row-major, coalesced vector loads
#pragma unroll
            for (int i = 0; i < 4; ++i) {
                int c = tid + i * 256;           // 0..1023
                int srow = c >> 4;               // 0..63
                int d0 = (c & 15) * 8;
                *(uint4*)&sK[srow][d0] = *(const uint4*)&Kc[(size_t)(tbase + kb + srow) * D_ + d0];
            }
            // stage V transposed: srow = c&63 so consecutive lanes write
            // consecutive sVt elements (2-way bank alias = free; was 16-way)
#pragma unroll
            for (int i = 0; i < 4; ++i) {
                int c = tid + i * 256;
                int srow = c & 63;
                int d0 = (c >> 6) * 8;
                bf16x8 v = *(const bf16x8*)&Vc[(size_t)(tbase + kb + srow) * D_ + d0];
#pragma unroll
                for (int j = 0; j < 8; ++j) sVt[d0 + j][srow] = v[j];
            }
            __syncthreads();

            // QK^T: per wave 32x64 scores
            f32x4 sc[2][4];
#pragma unroll
            for (int mt = 0; mt < 2; ++mt)
#pragma unroll
                for (int nt = 0; nt < 4; ++nt)
#pragma unroll
                    for (int r = 0; r < 4; ++r) sc[mt][nt][r] = 0.f;
#pragma unroll
            for (int ks = 0; ks < 4; ++ks) {
                bf16x8 bk[4];
#pragma unroll
                for (int nt = 0; nt < 4; ++nt)
                    bk[nt] = *(const bf16x8*)&sK[nt * 16 + col][ks * 32 + quad * 8];
#pragma unroll
                for (int mt = 0; mt < 2; ++mt)
#pragma unroll
                    for (int nt = 0; nt < 4; ++nt)
                        sc[mt][nt] = __builtin_amdgcn_mfma_f32_16x16x32_bf16(
                            aq[mt][ks], bk[nt], sc[mt][nt], 0, 0, 0);
            }

            // scale + causal mask + online softmax
#pragma unroll
            for (int mt = 0; mt < 2; ++mt) {
#pragma unroll
                for (int r = 0; r < 4; ++r) {
                    int qrow = qb + wave * 32 + mt * 16 + quad * 4 + r;
#pragma unroll
                    for (int nt = 0; nt < 4; ++nt) {
                        float v = sc[mt][nt][r] * scale;
                        int kcol = kb + nt * 16 + col;
                        sc[mt][nt][r] = (kcol > qrow) ? -3.0e38f : v;
                    }
                    float mx = sc[mt][0][r];
#pragma unroll
                    for (int nt = 1; nt < 4; ++nt) mx = fmaxf(mx, sc[mt][nt][r]);
#pragma unroll
                    for (int x = 1; x < 16; x <<= 1) mx = fmaxf(mx, __shfl_xor(mx, x, 64));
                    float mnew = fmaxf(m_i[mt][r], mx);
                    float alpha = __expf(m_i[mt][r] - mnew);
                    m_i[mt][r] = mnew;
                    float rs = 0.f;
#pragma unroll
                    for (int nt = 0; nt < 4; ++nt) {
                        float p = __expf(sc[mt][nt][r] - mnew);
                        sc[mt][nt][r] = p;
                        rs += p;
                    }
#pragma unroll
                    for (int x = 1; x < 16; x <<= 1) rs += __shfl_xor(rs, x, 64);
                    l_i[mt][r] = l_i[mt][r] * alpha + rs;
#pragma unroll
                    for (int nd = 0; nd < 8; ++nd) o[mt][nd][r] *= alpha;
                }
            }

            // P: C-layout regs -> per-wave LDS; same-wave RAW needs NO barrier
#pragma unroll
            for (int mt = 0; mt < 2; ++mt)
#pragma unroll
                for (int nt = 0; nt < 4; ++nt)
#pragma unroll
                    for (int r = 0; r < 4; ++r)
                        sP[wave][mt * 16 + quad * 4 + r][nt * 16 + col] = (__bf16)sc[mt][nt][r];

            // PV: O(32 x 128) += P(32 x 64) * V(64 x 128)
#pragma unroll
            for (int ks2 = 0; ks2 < 2; ++ks2) {
                bf16x8 ap[2];
#pragma unroll
                for (int mt = 0; mt < 2; ++mt)
                    ap[mt] = *(const bf16x8*)&sP[wave][mt * 16 + col][ks2 * 32 + quad * 8];
#pragma unroll
                for (int nd = 0; nd < 8; ++nd) {
                    bf16x8 bv = *(const bf16x8*)&sVt[nd * 16 + col][ks2 * 32 + quad * 8];
#pragma unroll
                    for (int mt = 0; mt < 2; ++mt)
                        o[mt][nd] = __builtin_amdgcn_mfma_f32_16x16x32_bf16(
                            ap[mt], bv, o[mt][nd], 0, 0, 0);
                }
            }
        }

        // epilogue: O /= l, write bf16 (T, HID)
#pragma unroll
        for (int mt = 0; mt < 2; ++mt) {
#pragma unroll
            for (int r = 0; r < 4; ++r) {
                int t = tbase + qb + wave * 32 + mt * 16 + quad * 4 + r;
                float inv_l = 1.f / l_i[mt][r];
#pragma unroll
                for (int nd = 0; nd < 8; ++nd)
                    O[(size_t)t * HID_ + h * 128 + nd * 16 + col] = (__bf16)(o[mt][nd][r] * inv_l);
            }
        }
    }
}

// ---------------------------------------------------------------- launch
extern "C" void kernel_launch(void* const* d_in, const int* in_sizes, int n_in,
                              void* d_out, int out_size, void* d_ws, size_t ws_size,
                              hipStream_t stream)
{
    const float* hidden  = (const float*)d_in[0];
    const float* cosb    = (const float*)d_in[1];
    const float* sinb    = (const float*)d_in[2];
    const float* kc_in   = (const float*)d_in[3];
    const float* vc_in   = (const float*)d_in[4];
    const float* qkv_w   = (const float*)d_in[5];
    const float* qkv_b   = (const float*)d_in[6];
    const float* dense_w = (const float*)d_in[7];
    const float* dense_b = (const float*)d_in[8];
    const int*   slots   = (const int*)d_in[9];

    float* out    = (float*)d_out;
    float* kc_out = out + (size_t)T_ * HID_;
    float* vc_out = kc_out + (size_t)NSLOTS_ * D_;

    char* ws = (char*)d_ws;
    __bf16* A16 = (__bf16*)(ws);
    __bf16* W1T = (__bf16*)(ws + 33554432);
    float*  QKV = (float*)(ws + 69206016);
    __bf16* W2T = (__bf16*)(ws + 69206016);   // alias: qkv f32 dead after rope
    __bf16* Q16 = (__bf16*)d_out;             // staged in out region (dead before GEMM2)
    __bf16* K16 = (__bf16*)((char*)d_out + 33554432);
    __bf16* V16 = (__bf16*)((char*)d_out + 34603008);

    cast_bf16_kernel<<<(T_ * HID_ / 4 + 255) / 256, 256, 0, stream>>>(hidden, A16, T_ * HID_ / 4);
    transpose_cast_kernel<<<dim3(NQKV_ / 32, HID_ / 32), dim3(32, 8), 0, stream>>>(qkv_w, W1T, HID_, NQKV_);
    gemm_bf16_kernel<<<dim3(NQKV_ / 128, T_ / 128), 256, 0, stream>>>(A16, W1T, qkv_b, QKV, T_, NQKV_, HID_);
    hipMemcpyAsync(kc_out, kc_in, (size_t)NSLOTS_ * D_ * 4, hipMemcpyDeviceToDevice, stream);
    hipMemcpyAsync(vc_out, vc_in, (size_t)NSLOTS_ * D_ * 4, hipMemcpyDeviceToDevice, stream);
    rope_scatter_kernel<<<T_, 256, 0, stream>>>(QKV, cosb, sinb, slots, Q16, K16, V16, kc_out, vc_out);
    transpose_cast_kernel<<<dim3(HID_ / 32, HID_ / 32), dim3(32, 8), 0, stream>>>(dense_w, W2T, HID_, HID_);
    attn_kernel<<<dim3(4, H_, B_), 256, 0, stream>>>(Q16, K16, V16, A16);
    gemm_bf16_kernel<<<dim3(HID_ / 128, T_ / 128), 256, 0, stream>>>(A16, W2T, dense_b, out, T_, HID_, HID_);
}